// Round 4
// baseline (59.876 us; speedup 1.0000x reference)
//
#include <hip/hip_runtime.h>

// Acrobot GN step, fused bf16-MFMA implementation. rows = 2*B.
//   G1: e1  = relu(A1 @ in32)            A1 = [We1[10:17];be1]^T, K=32 (bias via const-1 feat)
//   G2: e2  = relu(A2 @ e1 + be2)        A2 = We2^T, K=128
//   G3: hdd = relu(A3 @ [e2[row^1]; nodefeat]) K=160: main 128 = Wn1[12:140]^T over swapped rows,
//             ext 32 = [Wn1r10, Wn1r11, bn1, 0...] x B4(xa, xb, 1) built in-register
//   G4: delta = A4 @ hdd                 A4 = Wn2^T padded [16][128], K=128 MFMA
// out = x + scatter(delta) + bn2
//
// R3: pad LDS to 84KB (pdelta lives in the pad). 64KB allowed 2 WG/CU -> allocator
//     targeted 4 waves/SIMD -> 128-VGPR cap -> ~100 regs of weights spilled to scratch
//     (11MB WRITE_SIZE). Grid=256 on 256 CUs means only 1 WG/CU is resident anyway,
//     so >80KB LDS costs nothing and doubles the register budget to 256.

typedef __attribute__((ext_vector_type(8))) short bf16x8;
typedef __attribute__((ext_vector_type(4))) float f32x4;

__device__ __forceinline__ unsigned short f2bf(float f) {
  union { float f; unsigned u; } v; v.f = f;
  return (unsigned short)((v.u + 0x7FFFu + ((v.u >> 16) & 1u)) >> 16);  // RNE
}

// ---------------- weight prep: bf16 transposed A-operand images in ws ----------------
// shorts: A1 [128][32] @0 ; A2 [128][128] @4096 ; A3 [128][128] @20480 ;
//         A3ext [128][32] @36864 ; A4 [16][128] @40960 ; total 43008 shorts = 86016 B
__global__ void gn_prep(const float* __restrict__ We1, const float* __restrict__ be1,
                        const float* __restrict__ We2, const float* __restrict__ Wn1,
                        const float* __restrict__ bn1, const float* __restrict__ Wn2,
                        unsigned short* __restrict__ wsA) {
  int t = blockIdx.x * 256 + threadIdx.x;
  if (t < 4096) {                       // A1: k<7 -> We1 rows 10..16 ; k==7 -> be1
    int j = t >> 5, k = t & 31;
    float v = (k < 7) ? We1[(10 + k) * 128 + j] : ((k == 7) ? be1[j] : 0.0f);
    wsA[t] = f2bf(v);
  } else if (t < 20480) {               // A2 = We2^T
    int t2 = t - 4096; int j = t2 >> 7, k = t2 & 127;
    wsA[t] = f2bf(We2[k * 128 + j]);
  } else if (t < 36864) {               // A3 main = Wn1[12:140]^T
    int t2 = t - 20480; int j = t2 >> 7, k = t2 & 127;
    wsA[t] = f2bf(Wn1[(12 + k) * 128 + j]);
  } else if (t < 40960) {               // A3 ext: c0=Wn1r10, c1=Wn1r11, c2=bn1
    int t2 = t - 36864; int j = t2 >> 5, c = t2 & 31;
    float v = (c == 0) ? Wn1[10 * 128 + j] : (c == 1) ? Wn1[11 * 128 + j]
            : (c == 2) ? bn1[j] : 0.0f;
    wsA[t] = f2bf(v);
  } else if (t < 43008) {               // A4 = Wn2^T padded to 16 rows
    int t2 = t - 40960; int jp = t2 >> 7, k = t2 & 127;
    wsA[t] = f2bf((jp < 2) ? Wn2[k * 2 + jp] : 0.0f);
  }
}

// ---------------- main fused kernel ----------------
#define NTILES 2048   // 262144 rows / 128 rows per tile

__global__ __launch_bounds__(512) __attribute__((amdgpu_waves_per_eu(2, 2)))
void gn_main(
    const float* __restrict__ x, const float* __restrict__ u,
    const float* __restrict__ nmean, const float* __restrict__ nstd,
    const float* __restrict__ emean, const float* __restrict__ estd,
    const float* __restrict__ be2, const float* __restrict__ bn2,
    const unsigned short* __restrict__ wsA,
    float* __restrict__ out)
{
  // bufA: in32 (stage0->G1, 8KB) then e2 (G2->G3)
  // bufB: e1 (G1->G2) then hdd (G3->G4)
  // pad : occupancy limiter (force 1 WG/CU -> 256-VGPR budget); pdelta lives here
  __shared__ __align__(16) unsigned short bufA[128 * 128];
  __shared__ __align__(16) unsigned short bufB[128 * 128];
  __shared__ __align__(16) unsigned short pad[10240];        // 20KB; total 84KB LDS

  const int tid  = threadIdx.x;
  const int lane = tid & 63;
  const int wave = tid >> 6;
  const int Mg   = wave & 1;    // M half (feature dim half)
  const int Ng   = wave >> 1;   // N group (row groups of 32)
  const int c15  = lane & 15;
  const int g    = lane >> 4;   // 0..3

  // ---- A-operand fragments, loaded once, held in VGPRs ----
  bf16x8 A1f[4], A2f[4][4], A3f[4][5], A4f[4];
  const int jbw = Mg * 64;
  #pragma unroll
  for (int m = 0; m < 4; ++m) {
    int j = jbw + m * 16 + c15;
    A1f[m] = *(const bf16x8*)(wsA + j * 32 + g * 8);
    #pragma unroll
    for (int kk = 0; kk < 4; ++kk) {
      A2f[m][kk] = *(const bf16x8*)(wsA + 4096  + j * 128 + kk * 32 + g * 8);
      A3f[m][kk] = *(const bf16x8*)(wsA + 20480 + j * 128 + kk * 32 + g * 8);
    }
    A3f[m][4] = *(const bf16x8*)(wsA + 36864 + j * 32 + g * 8);
  }
  #pragma unroll
  for (int kk = 0; kk < 4; ++kk)
    A4f[kk] = *(const bf16x8*)(wsA + 40960 + c15 * 128 + kk * 32 + g * 8);

  const float nm0 = nmean[0], nm1 = nmean[1];
  const float is0 = 1.0f / nstd[0], is1 = 1.0f / nstd[1];
  const float em0 = emean[0], ie0 = 1.0f / estd[0];
  const float cea1 = (0.0f - emean[1]) / estd[1];
  const float cea2 = (0.0f - emean[2]) / estd[2];
  const float bn20 = bn2[0], bn21 = bn2[1];

  for (int tile = blockIdx.x; tile < NTILES; tile += gridDim.x) {
    const int rowbase = tile * 128;

    // ---------- stage0: build in32 (bf16, k=0..7 used) into bufA prefix ----------
    {
      int row = tid & 127;
      int cc  = tid >> 7;                       // 16B chunk 0..3 (wave-uniform)
      int off = row * 64 + ((cc * 16) ^ ((row & 3) << 4));
      bf16x8 val;
      #pragma unroll
      for (int i = 0; i < 8; ++i) val[i] = 0;
      if (cc == 0) {
        int gr = rowbase + row;
        int b = gr >> 1, e = gr & 1;
        const float4 xv = *(const float4*)(x + b * 4);
        float uv = u[b];
        float a0 = (xv.x - nm0) * is0;  // node0 theta
        float a1 = (xv.z - nm1) * is1;  // node0 v
        float b0 = (xv.y - nm0) * is0;  // node1 theta
        float b1 = (xv.w - nm1) * is1;  // node1 v
        float s0 = e ? b0 : a0, s1 = e ? b1 : a1;   // sender  = node e
        float r0 = e ? a0 : b0, r1 = e ? a1 : b1;   // receiver= node 1-e
        float ea0 = (uv - em0) * ie0;
        val[0] = (short)f2bf(s0);  val[1] = (short)f2bf(s1);
        val[2] = (short)f2bf(r0);  val[3] = (short)f2bf(r1);
        val[4] = (short)f2bf(ea0); val[5] = (short)f2bf(cea1);
        val[6] = (short)f2bf(cea2); val[7] = (short)f2bf(1.0f);
      }
      *(bf16x8*)((char*)bufA + off) = val;
    }
    __syncthreads();

    // ---------- G1: e1 = relu(A1 @ in32) -> bufB ----------
    {
      f32x4 acc[4][2];
      #pragma unroll
      for (int m = 0; m < 4; ++m)
        #pragma unroll
        for (int n = 0; n < 2; ++n) acc[m][n] = (f32x4){0.f, 0.f, 0.f, 0.f};
      #pragma unroll
      for (int n = 0; n < 2; ++n) {
        int row = (Ng * 2 + n) * 16 + c15;
        bf16x8 B = *(const bf16x8*)((const char*)bufA + row * 64 + ((g * 16) ^ ((row & 3) << 4)));
        #pragma unroll
        for (int m = 0; m < 4; ++m)
          acc[m][n] = __builtin_amdgcn_mfma_f32_16x16x32_bf16(A1f[m], B, acc[m][n], 0, 0, 0);
      }
      #pragma unroll
      for (int m = 0; m < 4; ++m) {
        int jb2 = (jbw + m * 16 + g * 4) * 2;
        #pragma unroll
        for (int n = 0; n < 2; ++n) {
          int row = (Ng * 2 + n) * 16 + c15;
          f32x4 v = acc[m][n];
          uint2 pk;
          pk.x = (unsigned)f2bf(fmaxf(v[0], 0.f)) | ((unsigned)f2bf(fmaxf(v[1], 0.f)) << 16);
          pk.y = (unsigned)f2bf(fmaxf(v[2], 0.f)) | ((unsigned)f2bf(fmaxf(v[3], 0.f)) << 16);
          *(uint2*)((char*)bufB + row * 256 + (jb2 ^ ((row & 7) << 4))) = pk;
        }
      }
    }
    __syncthreads();

    // ---------- G2: e2 = relu(A2 @ e1 + be2) -> bufA ----------
    {
      f32x4 acc[4][2];
      #pragma unroll
      for (int m = 0; m < 4; ++m)
        #pragma unroll
        for (int n = 0; n < 2; ++n) acc[m][n] = (f32x4){0.f, 0.f, 0.f, 0.f};
      #pragma unroll
      for (int n = 0; n < 2; ++n) {
        int row = (Ng * 2 + n) * 16 + c15;
        int rb = row * 256, sw = (row & 7) << 4;
        #pragma unroll
        for (int kk = 0; kk < 4; ++kk) {
          bf16x8 B = *(const bf16x8*)((const char*)bufB + rb + ((kk * 64 + g * 16) ^ sw));
          #pragma unroll
          for (int m = 0; m < 4; ++m)
            acc[m][n] = __builtin_amdgcn_mfma_f32_16x16x32_bf16(A2f[m][kk], B, acc[m][n], 0, 0, 0);
        }
      }
      #pragma unroll
      for (int m = 0; m < 4; ++m) {
        int jb = jbw + m * 16 + g * 4;
        f32x4 bz = *(const f32x4*)(be2 + jb);
        #pragma unroll
        for (int n = 0; n < 2; ++n) {
          int row = (Ng * 2 + n) * 16 + c15;
          f32x4 v = acc[m][n];
          uint2 pk;
          pk.x = (unsigned)f2bf(fmaxf(v[0] + bz[0], 0.f)) | ((unsigned)f2bf(fmaxf(v[1] + bz[1], 0.f)) << 16);
          pk.y = (unsigned)f2bf(fmaxf(v[2] + bz[2], 0.f)) | ((unsigned)f2bf(fmaxf(v[3] + bz[3], 0.f)) << 16);
          *(uint2*)((char*)bufA + row * 256 + ((jb * 2) ^ ((row & 7) << 4))) = pk;
        }
      }
    }
    __syncthreads();

    // ---------- G3: hdd = relu(A3 @ [e2[row^1]; nodefeat]) -> bufB ----------
    {
      f32x4 acc[4][2];
      #pragma unroll
      for (int m = 0; m < 4; ++m)
        #pragma unroll
        for (int n = 0; n < 2; ++n) acc[m][n] = (f32x4){0.f, 0.f, 0.f, 0.f};
      #pragma unroll
      for (int n = 0; n < 2; ++n) {
        int rr0 = (Ng * 2 + n) * 16 + c15;
        int rsw = rr0 ^ 1;                       // aggregation = paired-row swap
        int rb = rsw * 256, sw = (rsw & 7) << 4;
        #pragma unroll
        for (int kk = 0; kk < 4; ++kk) {
          bf16x8 B = *(const bf16x8*)((const char*)bufA + rb + ((kk * 64 + g * 16) ^ sw));
          #pragma unroll
          for (int m = 0; m < 4; ++m)
            acc[m][n] = __builtin_amdgcn_mfma_f32_16x16x32_bf16(A3f[m][kk], B, acc[m][n], 0, 0, 0);
        }
        // K-chunk 4: node features (xa, xb, 1) live only in g==0 lanes' k=128..130
        bf16x8 B4;
        #pragma unroll
        for (int i = 0; i < 8; ++i) B4[i] = 0;
        if (g == 0) {
          int gr = rowbase + rr0;
          int b = gr >> 1, k = gr & 1;
          float xa = (x[b * 4 + k]     - nm0) * is0;
          float xb = (x[b * 4 + k + 2] - nm1) * is1;
          B4[0] = (short)f2bf(xa); B4[1] = (short)f2bf(xb);
          B4[2] = (short)0x3F80;   // bf16 1.0
        }
        #pragma unroll
        for (int m = 0; m < 4; ++m)
          acc[m][n] = __builtin_amdgcn_mfma_f32_16x16x32_bf16(A3f[m][4], B4, acc[m][n], 0, 0, 0);
      }
      #pragma unroll
      for (int m = 0; m < 4; ++m) {
        int jb2 = (jbw + m * 16 + g * 4) * 2;
        #pragma unroll
        for (int n = 0; n < 2; ++n) {
          int row = (Ng * 2 + n) * 16 + c15;
          f32x4 v = acc[m][n];
          uint2 pk;
          pk.x = (unsigned)f2bf(fmaxf(v[0], 0.f)) | ((unsigned)f2bf(fmaxf(v[1], 0.f)) << 16);
          pk.y = (unsigned)f2bf(fmaxf(v[2], 0.f)) | ((unsigned)f2bf(fmaxf(v[3], 0.f)) << 16);
          *(uint2*)((char*)bufB + row * 256 + (jb2 ^ ((row & 7) << 4))) = pk;
        }
      }
    }
    __syncthreads();

    // ---------- G4: delta = A4 @ hdd (each wave does one 16-row group) ----------
    {
      int rr = (Ng * 2 + Mg) * 16 + c15;
      int rb = rr * 256, sw = (rr & 7) << 4;
      f32x4 a4 = (f32x4){0.f, 0.f, 0.f, 0.f};
      #pragma unroll
      for (int kk = 0; kk < 4; ++kk) {
        bf16x8 B = *(const bf16x8*)((const char*)bufB + rb + ((kk * 64 + g * 16) ^ sw));
        a4 = __builtin_amdgcn_mfma_f32_16x16x32_bf16(A4f[kk], B, a4, 0, 0, 0);
      }
      if (g == 0) {          // rows j'=0,1 of D = delta c0,c1 for col rr
        float2 w; w.x = a4[0]; w.y = a4[1];
        *(float2*)((char*)pad + rr * 8) = w;
      }
    }
    __syncthreads();

    // ---------- stage4: add bn2 and x, coalesced store ----------
    if (tid < 256) {
      const float* pd = (const float*)pad;
      int rr = 2 * (tid >> 2) + (tid & 1);
      int c  = (tid >> 1) & 1;
      float d = pd[rr * 2 + c] + (c ? bn21 : bn20);
      int gi = rowbase * 2 + tid;      // == b*4 + (k + 2c), coalesced
      out[gi] = x[gi] + d;
    }
    // next stage0 writes bufA — disjoint from pad; multiple barriers separate
    // stage4's pad reads from the next iteration's G4 pad writes. Safe.
  }
}

extern "C" void kernel_launch(void* const* d_in, const int* in_sizes, int n_in,
                              void* d_out, int out_size, void* d_ws, size_t ws_size,
                              hipStream_t stream) {
  const float* x   = (const float*)d_in[0];
  const float* u   = (const float*)d_in[1];
  const float* nm  = (const float*)d_in[2];
  const float* ns  = (const float*)d_in[3];
  const float* em  = (const float*)d_in[4];
  const float* es  = (const float*)d_in[5];
  const float* We1 = (const float*)d_in[6];
  const float* be1 = (const float*)d_in[7];
  const float* We2 = (const float*)d_in[8];
  const float* be2 = (const float*)d_in[9];
  const float* Wn1 = (const float*)d_in[10];
  const float* bn1 = (const float*)d_in[11];
  const float* Wn2 = (const float*)d_in[12];
  const float* bn2 = (const float*)d_in[13];
  unsigned short* wsA = (unsigned short*)d_ws;   // needs 86016 bytes
  float* out = (float*)d_out;

  gn_prep<<<168, 256, 0, stream>>>(We1, be1, We2, Wn1, bn1, Wn2, wsA);
  gn_main<<<256, 512, 0, stream>>>(x, u, nm, ns, em, es, be2, bn2, wsA, out);
}

// Round 5
// 54.287 us; speedup vs baseline: 1.1029x; 1.1029x over previous
//
#include <hip/hip_runtime.h>

// Acrobot GN step, fused bf16-MFMA implementation. rows = 2*B.
//   G1: e1  = relu(A1 @ in32)            A1 = [We1[10:17];be1]^T, K=32; B built IN REGISTERS
//   G2: e2  = relu(A2 @ e1 + be2)        A2 = We2^T, K=128
//   G3: hdd = relu(A3 @ [e2[row^1]; nodefeat]) K=160; nodefeat = sender feats saved from G1
//   G4: delta = A4 @ hdd                 A4 = Wn2^T padded [16][128], K=128 MFMA
// out = x + scatter(delta) + bn2
//
// R4 post-mortem: allocator ignores LDS size (VGPR_Count pinned at 128 arch + ~128 AGPR);
// time is latency-bound serialization (5 barriers, 1 barrier domain/CU, all pipes <25%).
// R5: 256-thread WGs (grid 512, 64-row tiles) -> 2 independent barrier domains per CU
//     (register file fits exactly 2 WGs at ~256 regs/wave); stage0 folded into G1
//     (B-operand built in registers, sender feats reused as G3's node feats) -> 4 barriers.

typedef __attribute__((ext_vector_type(8))) short bf16x8;
typedef __attribute__((ext_vector_type(4))) float f32x4;

__device__ __forceinline__ unsigned short f2bf(float f) {
  union { float f; unsigned u; } v; v.f = f;
  return (unsigned short)((v.u + 0x7FFFu + ((v.u >> 16) & 1u)) >> 16);  // RNE
}

// ---------------- weight prep: bf16 transposed A-operand images in ws ----------------
// shorts: A1 [128][32] @0 ; A2 [128][128] @4096 ; A3 [128][128] @20480 ;
//         A3ext [128][32] @36864 ; A4 [16][128] @40960 ; total 43008 shorts = 86016 B
__global__ void gn_prep(const float* __restrict__ We1, const float* __restrict__ be1,
                        const float* __restrict__ We2, const float* __restrict__ Wn1,
                        const float* __restrict__ bn1, const float* __restrict__ Wn2,
                        unsigned short* __restrict__ wsA) {
  int t = blockIdx.x * 256 + threadIdx.x;
  if (t < 4096) {                       // A1: k<7 -> We1 rows 10..16 ; k==7 -> be1
    int j = t >> 5, k = t & 31;
    float v = (k < 7) ? We1[(10 + k) * 128 + j] : ((k == 7) ? be1[j] : 0.0f);
    wsA[t] = f2bf(v);
  } else if (t < 20480) {               // A2 = We2^T
    int t2 = t - 4096; int j = t2 >> 7, k = t2 & 127;
    wsA[t] = f2bf(We2[k * 128 + j]);
  } else if (t < 36864) {               // A3 main = Wn1[12:140]^T
    int t2 = t - 20480; int j = t2 >> 7, k = t2 & 127;
    wsA[t] = f2bf(Wn1[(12 + k) * 128 + j]);
  } else if (t < 40960) {               // A3 ext: c0=Wn1r10, c1=Wn1r11, c2=bn1
    int t2 = t - 36864; int j = t2 >> 5, c = t2 & 31;
    float v = (c == 0) ? Wn1[10 * 128 + j] : (c == 1) ? Wn1[11 * 128 + j]
            : (c == 2) ? bn1[j] : 0.0f;
    wsA[t] = f2bf(v);
  } else if (t < 43008) {               // A4 = Wn2^T padded to 16 rows
    int t2 = t - 40960; int jp = t2 >> 7, k = t2 & 127;
    wsA[t] = f2bf((jp < 2) ? Wn2[k * 2 + jp] : 0.0f);
  }
}

// ---------------- main fused kernel ----------------
#define NTILES 4096   // 262144 rows / 64 rows per tile

__global__ __launch_bounds__(256) __attribute__((amdgpu_waves_per_eu(2, 2)))
void gn_main(
    const float* __restrict__ x, const float* __restrict__ u,
    const float* __restrict__ nmean, const float* __restrict__ nstd,
    const float* __restrict__ emean, const float* __restrict__ estd,
    const float* __restrict__ be2, const float* __restrict__ bn2,
    const unsigned short* __restrict__ wsA,
    float* __restrict__ out)
{
  // 64 rows/tile. bufA: e2 (G2->G3). bufB: e1 (G1->G2) then hdd (G3->G4).
  // pdelta oversized to land total LDS at 64KB -> exactly 2 WGs/CU.
  __shared__ __align__(16) unsigned short bufA[64 * 128];   // 16KB
  __shared__ __align__(16) unsigned short bufB[64 * 128];   // 16KB
  __shared__ __align__(16) float pdelta[8192];              // 32KB (first 128 used)

  const int tid  = threadIdx.x;
  const int lane = tid & 63;
  const int wave = tid >> 6;     // 0..3
  const int Mg   = wave & 1;     // M half (feature dim half)
  const int Ng   = wave >> 1;    // N group (row groups of 32) 0..1
  const int c15  = lane & 15;
  const int g    = lane >> 4;    // 0..3

  // ---- A-operand fragments, loaded once, held in VGPRs/AGPRs ----
  bf16x8 A1f[4], A2f[4][4], A3f[4][5], A4f[4];
  const int jbw = Mg * 64;
  #pragma unroll
  for (int m = 0; m < 4; ++m) {
    int j = jbw + m * 16 + c15;
    A1f[m] = *(const bf16x8*)(wsA + j * 32 + g * 8);
    #pragma unroll
    for (int kk = 0; kk < 4; ++kk) {
      A2f[m][kk] = *(const bf16x8*)(wsA + 4096  + j * 128 + kk * 32 + g * 8);
      A3f[m][kk] = *(const bf16x8*)(wsA + 20480 + j * 128 + kk * 32 + g * 8);
    }
    A3f[m][4] = *(const bf16x8*)(wsA + 36864 + j * 32 + g * 8);
  }
  #pragma unroll
  for (int kk = 0; kk < 4; ++kk)
    A4f[kk] = *(const bf16x8*)(wsA + 40960 + c15 * 128 + kk * 32 + g * 8);

  const float nm0 = nmean[0], nm1 = nmean[1];
  const float is0 = 1.0f / nstd[0], is1 = 1.0f / nstd[1];
  const float em0 = emean[0], ie0 = 1.0f / estd[0];
  const float cea1 = (0.0f - emean[1]) / estd[1];
  const float cea2 = (0.0f - emean[2]) / estd[2];
  const float bn20 = bn2[0], bn21 = bn2[1];
  const unsigned short cea1b = f2bf(cea1), cea2b = f2bf(cea2);

  for (int tile = blockIdx.x; tile < NTILES; tile += gridDim.x) {
    const int rowbase = tile * 64;
    unsigned pks[2];   // packed bf16 (s0,s1) per n — G1 B-operand dword0, reused as G3 B4

    // ---------- G1: build B in registers, e1 = relu(A1 @ in32) -> bufB ----------
    {
      f32x4 acc[4][2];
      #pragma unroll
      for (int m = 0; m < 4; ++m)
        #pragma unroll
        for (int n = 0; n < 2; ++n) acc[m][n] = (f32x4){0.f, 0.f, 0.f, 0.f};
      #pragma unroll
      for (int n = 0; n < 2; ++n) {
        int row = (Ng * 2 + n) * 16 + c15;
        bf16x8 B;
        #pragma unroll
        for (int i = 0; i < 8; ++i) B[i] = 0;
        pks[n] = 0;
        if (g == 0) {                       // only k=0..7 nonzero; lanes g==0 hold them
          int gr = rowbase + row;
          int b = gr >> 1, e = gr & 1;
          const float4 xv = *(const float4*)(x + b * 4);
          float uv = u[b];
          float a0 = (xv.x - nm0) * is0;    // node0 theta
          float a1 = (xv.z - nm1) * is1;    // node0 v
          float b0 = (xv.y - nm0) * is0;    // node1 theta
          float b1 = (xv.w - nm1) * is1;    // node1 v
          float s0 = e ? b0 : a0, s1 = e ? b1 : a1;   // sender = node e == node-row gr
          float r0 = e ? a0 : b0, r1 = e ? a1 : b1;   // receiver = node 1-e
          float ea0 = (uv - em0) * ie0;
          unsigned short s0b = f2bf(s0), s1b = f2bf(s1);
          B[0] = (short)s0b;        B[1] = (short)s1b;
          B[2] = (short)f2bf(r0);   B[3] = (short)f2bf(r1);
          B[4] = (short)f2bf(ea0);  B[5] = (short)cea1b;
          B[6] = (short)cea2b;      B[7] = (short)0x3F80;
          pks[n] = (unsigned)s0b | ((unsigned)s1b << 16);
        }
        #pragma unroll
        for (int m = 0; m < 4; ++m)
          acc[m][n] = __builtin_amdgcn_mfma_f32_16x16x32_bf16(A1f[m], B, acc[m][n], 0, 0, 0);
      }
      #pragma unroll
      for (int m = 0; m < 4; ++m) {
        int jb2 = (jbw + m * 16 + g * 4) * 2;
        #pragma unroll
        for (int n = 0; n < 2; ++n) {
          int row = (Ng * 2 + n) * 16 + c15;
          f32x4 v = acc[m][n];
          uint2 pk;
          pk.x = (unsigned)f2bf(fmaxf(v[0], 0.f)) | ((unsigned)f2bf(fmaxf(v[1], 0.f)) << 16);
          pk.y = (unsigned)f2bf(fmaxf(v[2], 0.f)) | ((unsigned)f2bf(fmaxf(v[3], 0.f)) << 16);
          *(uint2*)((char*)bufB + row * 256 + (jb2 ^ ((row & 7) << 4))) = pk;
        }
      }
    }
    __syncthreads();

    // ---------- G2: e2 = relu(A2 @ e1 + be2) -> bufA ----------
    {
      f32x4 acc[4][2];
      #pragma unroll
      for (int m = 0; m < 4; ++m)
        #pragma unroll
        for (int n = 0; n < 2; ++n) acc[m][n] = (f32x4){0.f, 0.f, 0.f, 0.f};
      #pragma unroll
      for (int n = 0; n < 2; ++n) {
        int row = (Ng * 2 + n) * 16 + c15;
        int rb = row * 256, sw = (row & 7) << 4;
        #pragma unroll
        for (int kk = 0; kk < 4; ++kk) {
          bf16x8 B = *(const bf16x8*)((const char*)bufB + rb + ((kk * 64 + g * 16) ^ sw));
          #pragma unroll
          for (int m = 0; m < 4; ++m)
            acc[m][n] = __builtin_amdgcn_mfma_f32_16x16x32_bf16(A2f[m][kk], B, acc[m][n], 0, 0, 0);
        }
      }
      #pragma unroll
      for (int m = 0; m < 4; ++m) {
        int jb = jbw + m * 16 + g * 4;
        f32x4 bz = *(const f32x4*)(be2 + jb);
        #pragma unroll
        for (int n = 0; n < 2; ++n) {
          int row = (Ng * 2 + n) * 16 + c15;
          f32x4 v = acc[m][n];
          uint2 pk;
          pk.x = (unsigned)f2bf(fmaxf(v[0] + bz[0], 0.f)) | ((unsigned)f2bf(fmaxf(v[1] + bz[1], 0.f)) << 16);
          pk.y = (unsigned)f2bf(fmaxf(v[2] + bz[2], 0.f)) | ((unsigned)f2bf(fmaxf(v[3] + bz[3], 0.f)) << 16);
          *(uint2*)((char*)bufA + row * 256 + ((jb * 2) ^ ((row & 7) << 4))) = pk;
        }
      }
    }
    __syncthreads();

    // ---------- G3: hdd = relu(A3 @ [e2[row^1]; nodefeat]) -> bufB ----------
    {
      f32x4 acc[4][2];
      #pragma unroll
      for (int m = 0; m < 4; ++m)
        #pragma unroll
        for (int n = 0; n < 2; ++n) acc[m][n] = (f32x4){0.f, 0.f, 0.f, 0.f};
      #pragma unroll
      for (int n = 0; n < 2; ++n) {
        int rr0 = (Ng * 2 + n) * 16 + c15;
        int rsw = rr0 ^ 1;                       // aggregation = paired-row swap
        int rb = rsw * 256, sw = (rsw & 7) << 4;
        #pragma unroll
        for (int kk = 0; kk < 4; ++kk) {
          bf16x8 B = *(const bf16x8*)((const char*)bufA + rb + ((kk * 64 + g * 16) ^ sw));
          #pragma unroll
          for (int m = 0; m < 4; ++m)
            acc[m][n] = __builtin_amdgcn_mfma_f32_16x16x32_bf16(A3f[m][kk], B, acc[m][n], 0, 0, 0);
        }
        // K-chunk 4: node feats (= sender feats of row rr0, saved from G1) + const 1
        bf16x8 B4;
        #pragma unroll
        for (int i = 0; i < 8; ++i) B4[i] = 0;
        if (g == 0) {
          B4[0] = (short)(pks[n] & 0xFFFFu);
          B4[1] = (short)(pks[n] >> 16);
          B4[2] = (short)0x3F80;   // bf16 1.0
        }
        #pragma unroll
        for (int m = 0; m < 4; ++m)
          acc[m][n] = __builtin_amdgcn_mfma_f32_16x16x32_bf16(A3f[m][4], B4, acc[m][n], 0, 0, 0);
      }
      #pragma unroll
      for (int m = 0; m < 4; ++m) {
        int jb2 = (jbw + m * 16 + g * 4) * 2;
        #pragma unroll
        for (int n = 0; n < 2; ++n) {
          int row = (Ng * 2 + n) * 16 + c15;
          f32x4 v = acc[m][n];
          uint2 pk;
          pk.x = (unsigned)f2bf(fmaxf(v[0], 0.f)) | ((unsigned)f2bf(fmaxf(v[1], 0.f)) << 16);
          pk.y = (unsigned)f2bf(fmaxf(v[2], 0.f)) | ((unsigned)f2bf(fmaxf(v[3], 0.f)) << 16);
          *(uint2*)((char*)bufB + row * 256 + (jb2 ^ ((row & 7) << 4))) = pk;
        }
      }
    }
    __syncthreads();

    // ---------- G4: delta = A4 @ hdd (each wave does one 16-row group) ----------
    {
      int rr = (Ng * 2 + Mg) * 16 + c15;
      int rb = rr * 256, sw = (rr & 7) << 4;
      f32x4 a4 = (f32x4){0.f, 0.f, 0.f, 0.f};
      #pragma unroll
      for (int kk = 0; kk < 4; ++kk) {
        bf16x8 B = *(const bf16x8*)((const char*)bufB + rb + ((kk * 64 + g * 16) ^ sw));
        a4 = __builtin_amdgcn_mfma_f32_16x16x32_bf16(A4f[kk], B, a4, 0, 0, 0);
      }
      if (g == 0) {          // rows j'=0,1 of D = delta c0,c1 for col rr
        float2 w; w.x = a4[0]; w.y = a4[1];
        *(float2*)(pdelta + rr * 2) = w;
      }
    }
    __syncthreads();

    // ---------- stage4: add bn2 and x, coalesced store ----------
    if (tid < 128) {
      int rr = 2 * (tid >> 2) + (tid & 1);
      int c  = (tid >> 1) & 1;
      float d = pdelta[rr * 2 + c] + (c ? bn21 : bn20);
      int gi = rowbase * 2 + tid;      // == b*4 + (k + 2c), coalesced
      out[gi] = x[gi] + d;
    }
    // next G1 writes bufB: safe (bar after G4's bufB reads); stage4 reads pdelta,
    // next pdelta write is 3 barriers away. No trailing barrier needed.
  }
}

extern "C" void kernel_launch(void* const* d_in, const int* in_sizes, int n_in,
                              void* d_out, int out_size, void* d_ws, size_t ws_size,
                              hipStream_t stream) {
  const float* x   = (const float*)d_in[0];
  const float* u   = (const float*)d_in[1];
  const float* nm  = (const float*)d_in[2];
  const float* ns  = (const float*)d_in[3];
  const float* em  = (const float*)d_in[4];
  const float* es  = (const float*)d_in[5];
  const float* We1 = (const float*)d_in[6];
  const float* be1 = (const float*)d_in[7];
  const float* We2 = (const float*)d_in[8];
  const float* be2 = (const float*)d_in[9];
  const float* Wn1 = (const float*)d_in[10];
  const float* bn1 = (const float*)d_in[11];
  const float* Wn2 = (const float*)d_in[12];
  const float* bn2 = (const float*)d_in[13];
  unsigned short* wsA = (unsigned short*)d_ws;   // needs 86016 bytes
  float* out = (float*)d_out;

  gn_prep<<<168, 256, 0, stream>>>(We1, be1, We2, Wn1, bn1, Wn2, wsA);
  gn_main<<<512, 256, 0, stream>>>(x, u, nm, ns, em, es, be2, bn2, wsA, out);
}

// Round 6
// 51.330 us; speedup vs baseline: 1.1665x; 1.0576x over previous
//
#include <hip/hip_runtime.h>

// Acrobot GN step, fused bf16-MFMA. rows = 2*B, 32 rows per 2-wave WG tile.
//   G1: e1  = relu(A1 @ in32)            A1=[We1[10:17];be1]^T, K=32; B built in regs
//   G2: e2  = relu(A2 @ e1 + be2)        A2=We2^T, K=128; be2 via MFMA C-init
//   G3: hdd = relu(A3 @ [e2[row^1]; sender,1]) K=160; bn1 folded in A3ext col2
//   G4: delta = A4 @ hdd + bn2           A4=Wn2^T pad [16][128]; bn2 via C-init; direct store
//
// R5 post-mortem: VALU (28%) was top pipe (manual f2bf bit-math), rest latency stall.
// R6: v_cvt_pk_bf16_f32 epilogues + bias-as-C-init (pure fmax+cvtpk epilogues);
//     128-thread WGs -> 4 barrier domains/CU, 3 barriers/tile, 3 LDS bufs;
//     x/u prefetched one tile ahead.

typedef __attribute__((ext_vector_type(8))) short bf16x8;
typedef __attribute__((ext_vector_type(4))) float f32x4;

union U4B { uint4 u; bf16x8 b; };

__device__ __forceinline__ unsigned short f2bf(float f) {
  union { float f; unsigned u; } v; v.f = f;
  return (unsigned short)((v.u + 0x7FFFu + ((v.u >> 16) & 1u)) >> 16);  // RNE
}

__device__ __forceinline__ unsigned cvtpk(float lo, float hi) {
  unsigned r;
  asm("v_cvt_pk_bf16_f32 %0, %1, %2" : "=v"(r) : "v"(lo), "v"(hi));
  return r;
}

// ---------------- weight prep: bf16 transposed A-operand images in ws ----------------
// shorts: A1 [128][32] @0 ; A2 [128][128] @4096 ; A3 [128][128] @20480 ;
//         A3ext [128][32] @36864 ; A4 [16][128] @40960 ; total 43008 shorts = 86016 B
__global__ void gn_prep(const float* __restrict__ We1, const float* __restrict__ be1,
                        const float* __restrict__ We2, const float* __restrict__ Wn1,
                        const float* __restrict__ bn1, const float* __restrict__ Wn2,
                        unsigned short* __restrict__ wsA) {
  int t = blockIdx.x * 256 + threadIdx.x;
  if (t < 4096) {                       // A1: k<7 -> We1 rows 10..16 ; k==7 -> be1
    int j = t >> 5, k = t & 31;
    float v = (k < 7) ? We1[(10 + k) * 128 + j] : ((k == 7) ? be1[j] : 0.0f);
    wsA[t] = f2bf(v);
  } else if (t < 20480) {               // A2 = We2^T
    int t2 = t - 4096; int j = t2 >> 7, k = t2 & 127;
    wsA[t] = f2bf(We2[k * 128 + j]);
  } else if (t < 36864) {               // A3 main = Wn1[12:140]^T
    int t2 = t - 20480; int j = t2 >> 7, k = t2 & 127;
    wsA[t] = f2bf(Wn1[(12 + k) * 128 + j]);
  } else if (t < 40960) {               // A3 ext: c0=Wn1r10, c1=Wn1r11, c2=bn1
    int t2 = t - 36864; int j = t2 >> 5, c = t2 & 31;
    float v = (c == 0) ? Wn1[10 * 128 + j] : (c == 1) ? Wn1[11 * 128 + j]
            : (c == 2) ? bn1[j] : 0.0f;
    wsA[t] = f2bf(v);
  } else if (t < 43008) {               // A4 = Wn2^T padded to 16 rows
    int t2 = t - 40960; int jp = t2 >> 7, k = t2 & 127;
    wsA[t] = f2bf((jp < 2) ? Wn2[k * 2 + jp] : 0.0f);
  }
}

// ---------------- main fused kernel ----------------
#define NTILES 8192   // 262144 rows / 32 rows per tile

__global__ __launch_bounds__(128) __attribute__((amdgpu_waves_per_eu(2, 2)))
void gn_main(
    const float* __restrict__ x, const float* __restrict__ u,
    const float* __restrict__ nmean, const float* __restrict__ nstd,
    const float* __restrict__ emean, const float* __restrict__ estd,
    const float* __restrict__ be2, const float* __restrict__ bn2,
    const unsigned short* __restrict__ wsA,
    float* __restrict__ out)
{
  __shared__ __align__(16) unsigned short bufE1[32 * 128];  // 8KB
  __shared__ __align__(16) unsigned short bufE2[32 * 128];  // 8KB
  __shared__ __align__(16) unsigned short bufHD[32 * 128];  // 8KB

  const int tid  = threadIdx.x;
  const int lane = tid & 63;
  const int Mg   = tid >> 6;     // wave = feature half 0/1
  const int c15  = lane & 15;
  const int g    = lane >> 4;    // 0..3

  // ---- A-operand fragments, loaded once, held in VGPRs/AGPRs ----
  bf16x8 A1f[4], A2f[4][4], A3f[4][5], A4f[4];
  const int jbw = Mg * 64;
  #pragma unroll
  for (int m = 0; m < 4; ++m) {
    int j = jbw + m * 16 + c15;
    A1f[m] = *(const bf16x8*)(wsA + j * 32 + g * 8);
    #pragma unroll
    for (int kk = 0; kk < 4; ++kk) {
      A2f[m][kk] = *(const bf16x8*)(wsA + 4096  + j * 128 + kk * 32 + g * 8);
      A3f[m][kk] = *(const bf16x8*)(wsA + 20480 + j * 128 + kk * 32 + g * 8);
    }
    A3f[m][4] = *(const bf16x8*)(wsA + 36864 + j * 32 + g * 8);
  }
  #pragma unroll
  for (int kk = 0; kk < 4; ++kk)
    A4f[kk] = *(const bf16x8*)(wsA + 40960 + c15 * 128 + kk * 32 + g * 8);

  const float nm0 = nmean[0], nm1 = nmean[1];
  const float is0 = 1.0f / nstd[0], is1 = 1.0f / nstd[1];
  const float em0 = emean[0], ie0 = 1.0f / estd[0];
  const float cea1 = (0.0f - emean[1]) / estd[1];
  const float cea2 = (0.0f - emean[2]) / estd[2];
  const float bn20 = bn2[0], bn21 = bn2[1];
  const unsigned cpkw = cvtpk(cea2, 1.0f);   // B dword3: [cea2, 1.0]

  // ---- prefetch first tile's x/u ----
  float4 xv[2]; float uv[2];
  {
    int t0 = blockIdx.x;
    if (g == 0) {
      #pragma unroll
      for (int n = 0; n < 2; ++n) {
        int b = t0 * 16 + n * 8 + (c15 >> 1);
        xv[n] = *(const float4*)(x + b * 4);
        uv[n] = u[b];
      }
    }
  }

  for (int tile = blockIdx.x; tile < NTILES; tile += gridDim.x) {
    const int rowbase = tile * 32;
    unsigned pks[2];
    bf16x8 Bv[2];

    // ---------- build G1 B-operands in registers ----------
    #pragma unroll
    for (int n = 0; n < 2; ++n) {
      uint4 bu = (uint4){0u, 0u, 0u, 0u};
      if (g == 0) {                     // only k=0..7 nonzero; g==0 lanes hold them
        float a0 = (xv[n].x - nm0) * is0;   // node0 theta
        float a1 = (xv[n].z - nm1) * is1;   // node0 v
        float b0 = (xv[n].y - nm0) * is0;   // node1 theta
        float b1 = (xv[n].w - nm1) * is1;   // node1 v
        bool  e  = (c15 & 1);               // row parity = edge index
        float s0 = e ? b0 : a0, s1 = e ? b1 : a1;   // sender  feats
        float r0 = e ? a0 : b0, r1 = e ? a1 : b1;   // receiver feats
        float ea0 = (uv[n] - em0) * ie0;
        bu.x = cvtpk(s0, s1);
        bu.y = cvtpk(r0, r1);
        bu.z = cvtpk(ea0, cea1);
        bu.w = cpkw;
      }
      pks[n] = bu.x;                    // sender feats, reused as G3 node feats
      U4B t; t.u = bu; Bv[n] = t.b;
    }

    // ---------- prefetch next tile's x/u (hidden under 3 barriers) ----------
    {
      int nt = tile + (int)gridDim.x;
      if (nt < NTILES && g == 0) {
        #pragma unroll
        for (int n = 0; n < 2; ++n) {
          int b = nt * 16 + n * 8 + (c15 >> 1);
          xv[n] = *(const float4*)(x + b * 4);
          uv[n] = u[b];
        }
      }
    }

    f32x4 acc[4][2];

    // ---------- G1: e1 = relu(A1 @ in32) -> bufE1 ----------
    #pragma unroll
    for (int m = 0; m < 4; ++m)
      #pragma unroll
      for (int n = 0; n < 2; ++n) acc[m][n] = (f32x4){0.f, 0.f, 0.f, 0.f};
    #pragma unroll
    for (int n = 0; n < 2; ++n)
      #pragma unroll
      for (int m = 0; m < 4; ++m)
        acc[m][n] = __builtin_amdgcn_mfma_f32_16x16x32_bf16(A1f[m], Bv[n], acc[m][n], 0, 0, 0);
    #pragma unroll
    for (int m = 0; m < 4; ++m) {
      int jb2 = (jbw + m * 16 + g * 4) * 2;
      #pragma unroll
      for (int n = 0; n < 2; ++n) {
        int row = n * 16 + c15;
        f32x4 v = acc[m][n];
        uint2 pk;
        pk.x = cvtpk(fmaxf(v[0], 0.f), fmaxf(v[1], 0.f));
        pk.y = cvtpk(fmaxf(v[2], 0.f), fmaxf(v[3], 0.f));
        *(uint2*)((char*)bufE1 + row * 256 + (jb2 ^ ((row & 7) << 4))) = pk;
      }
    }
    __syncthreads();

    // ---------- G2: e2 = relu(A2 @ e1 + be2) -> bufE2 (be2 as C-init) ----------
    #pragma unroll
    for (int m = 0; m < 4; ++m) {
      f32x4 bz = *(const f32x4*)(be2 + jbw + m * 16 + g * 4);
      acc[m][0] = bz; acc[m][1] = bz;
    }
    #pragma unroll
    for (int n = 0; n < 2; ++n) {
      int row = n * 16 + c15;
      int rb = row * 256, sw = (row & 7) << 4;
      #pragma unroll
      for (int kk = 0; kk < 4; ++kk) {
        bf16x8 B = *(const bf16x8*)((const char*)bufE1 + rb + ((kk * 64 + g * 16) ^ sw));
        #pragma unroll
        for (int m = 0; m < 4; ++m)
          acc[m][n] = __builtin_amdgcn_mfma_f32_16x16x32_bf16(A2f[m][kk], B, acc[m][n], 0, 0, 0);
      }
    }
    #pragma unroll
    for (int m = 0; m < 4; ++m) {
      int jb2 = (jbw + m * 16 + g * 4) * 2;
      #pragma unroll
      for (int n = 0; n < 2; ++n) {
        int row = n * 16 + c15;
        f32x4 v = acc[m][n];
        uint2 pk;
        pk.x = cvtpk(fmaxf(v[0], 0.f), fmaxf(v[1], 0.f));
        pk.y = cvtpk(fmaxf(v[2], 0.f), fmaxf(v[3], 0.f));
        *(uint2*)((char*)bufE2 + row * 256 + (jb2 ^ ((row & 7) << 4))) = pk;
      }
    }
    __syncthreads();

    // ---------- G3: hdd = relu(A3 @ [e2[row^1]; sender,1]) -> bufHD ----------
    #pragma unroll
    for (int m = 0; m < 4; ++m)
      #pragma unroll
      for (int n = 0; n < 2; ++n) acc[m][n] = (f32x4){0.f, 0.f, 0.f, 0.f};
    #pragma unroll
    for (int n = 0; n < 2; ++n) {
      int rr0 = n * 16 + c15;
      int rsw = rr0 ^ 1;                       // aggregation = paired-row swap
      int rb = rsw * 256, sw = (rsw & 7) << 4;
      #pragma unroll
      for (int kk = 0; kk < 4; ++kk) {
        bf16x8 B = *(const bf16x8*)((const char*)bufE2 + rb + ((kk * 64 + g * 16) ^ sw));
        #pragma unroll
        for (int m = 0; m < 4; ++m)
          acc[m][n] = __builtin_amdgcn_mfma_f32_16x16x32_bf16(A3f[m][kk], B, acc[m][n], 0, 0, 0);
      }
      // K-chunk 4: node feats (= sender feats saved from G1) + const-1 (bn1 column)
      uint4 b4u = (uint4){0u, 0u, 0u, 0u};
      if (g == 0) { b4u.x = pks[n]; b4u.y = 0x00003F80u; }
      U4B t4; t4.u = b4u;
      #pragma unroll
      for (int m = 0; m < 4; ++m)
        acc[m][n] = __builtin_amdgcn_mfma_f32_16x16x32_bf16(A3f[m][4], t4.b, acc[m][n], 0, 0, 0);
    }
    #pragma unroll
    for (int m = 0; m < 4; ++m) {
      int jb2 = (jbw + m * 16 + g * 4) * 2;
      #pragma unroll
      for (int n = 0; n < 2; ++n) {
        int row = n * 16 + c15;
        f32x4 v = acc[m][n];
        uint2 pk;
        pk.x = cvtpk(fmaxf(v[0], 0.f), fmaxf(v[1], 0.f));
        pk.y = cvtpk(fmaxf(v[2], 0.f), fmaxf(v[3], 0.f));
        *(uint2*)((char*)bufHD + row * 256 + (jb2 ^ ((row & 7) << 4))) = pk;
      }
    }
    __syncthreads();

    // ---------- G4: delta = A4 @ hdd + bn2 (C-init), store direct ----------
    {
      int rr = Mg * 16 + c15;
      int rb = rr * 256, sw = (rr & 7) << 4;
      f32x4 a4 = (f32x4){bn20, bn21, 0.f, 0.f};
      #pragma unroll
      for (int kk = 0; kk < 4; ++kk) {
        bf16x8 B = *(const bf16x8*)((const char*)bufHD + rb + ((kk * 64 + g * 16) ^ sw));
        a4 = __builtin_amdgcn_mfma_f32_16x16x32_bf16(A4f[kk], B, a4, 0, 0, 0);
      }
      if (g == 0) {                // lane holds delta c0,c1 for row rr
        int gr = rowbase + rr;
        int bidx = gr >> 1, k = gr & 1;
        out[bidx * 4 + k]     = x[bidx * 4 + k]     + a4[0];
        out[bidx * 4 + k + 2] = x[bidx * 4 + k + 2] + a4[1];
      }
    }
    // no trailing barrier: next G1 writes bufE1, whose last reads (G2) are 2 barriers back.
  }
}

extern "C" void kernel_launch(void* const* d_in, const int* in_sizes, int n_in,
                              void* d_out, int out_size, void* d_ws, size_t ws_size,
                              hipStream_t stream) {
  const float* x   = (const float*)d_in[0];
  const float* u   = (const float*)d_in[1];
  const float* nm  = (const float*)d_in[2];
  const float* ns  = (const float*)d_in[3];
  const float* em  = (const float*)d_in[4];
  const float* es  = (const float*)d_in[5];
  const float* We1 = (const float*)d_in[6];
  const float* be1 = (const float*)d_in[7];
  const float* We2 = (const float*)d_in[8];
  const float* be2 = (const float*)d_in[9];
  const float* Wn1 = (const float*)d_in[10];
  const float* bn1 = (const float*)d_in[11];
  const float* Wn2 = (const float*)d_in[12];
  const float* bn2 = (const float*)d_in[13];
  unsigned short* wsA = (unsigned short*)d_ws;   // needs 86016 bytes
  float* out = (float*)d_out;

  gn_prep<<<168, 256, 0, stream>>>(We1, be1, We2, Wn1, bn1, Wn2, wsA);
  gn_main<<<1024, 128, 0, stream>>>(x, u, nm, ns, em, es, be2, bn2, wsA, out);
}

// Round 7
// 42.569 us; speedup vs baseline: 1.4066x; 1.2058x over previous
//
#include <hip/hip_runtime.h>

// Acrobot GN step, fused bf16-MFMA. rows = 2*B, 32 rows per 2-wave WG tile.
//   G1: e1  = relu(A1 @ in32)            A1=[We1[10:17];be1]^T, K=32; B built in regs
//   G2: e2  = relu(A2 @ e1 + be2)        A2=We2^T, K=128; be2 via MFMA C-init
//   G3: hdd = relu(A3 @ [e2[row^1]; sender,1]) K=160; bn1 folded in A3ext col2
//   G4: delta = A4 @ hdd + bn2           A4=Wn2^T pad [16][128]; bn2 via C-init; direct store
//
// R6 post-mortem: WRITE_SIZE 12.5MB/dispatch = ~10.5MB scratch spill (fragment demand
// 176+32+60 ~ 270 > 256-reg budget); spill reloads serialize every stage (all pipes <20%).
// R7: A1/A3ext/A4 are sparse -> stored COMPACT (4.5KB), copied to LDS once, fragments
// ds_read per tile as transients. Resident frags drop 176->128 (=AGPR capacity); no spill.

typedef __attribute__((ext_vector_type(8))) short bf16x8;
typedef __attribute__((ext_vector_type(4))) float f32x4;

union U4B { uint4 u; bf16x8 b; };

__device__ __forceinline__ unsigned short f2bf(float f) {
  union { float f; unsigned u; } v; v.f = f;
  return (unsigned short)((v.u + 0x7FFFu + ((v.u >> 16) & 1u)) >> 16);  // RNE
}

__device__ __forceinline__ unsigned cvtpk(float lo, float hi) {
  unsigned r;
  asm("v_cvt_pk_bf16_f32 %0, %1, %2" : "=v"(r) : "v"(lo), "v"(hi));
  return r;
}

// ---------------- weight prep: bf16 A-operand images in ws ----------------
// shorts: A1c [128j][8k] @0 ; A3e [128j][8k] @1024 ; A4c [2jp][128k] @2048 (2304 total);
//         A2 [128j][128k] @4096 ; A3 main [128j][128k] @20480. 36864 shorts = 73728 B.
__global__ void gn_prep(const float* __restrict__ We1, const float* __restrict__ be1,
                        const float* __restrict__ We2, const float* __restrict__ Wn1,
                        const float* __restrict__ bn1, const float* __restrict__ Wn2,
                        unsigned short* __restrict__ wsA) {
  int t = blockIdx.x * 256 + threadIdx.x;
  if (t < 1024) {                       // A1 compact: k<7 -> We1 rows 10..16 ; k==7 -> be1
    int j = t >> 3, k = t & 7;
    wsA[t] = f2bf((k < 7) ? We1[(10 + k) * 128 + j] : be1[j]);
  } else if (t < 2048) {                // A3ext compact: c0=Wn1r10, c1=Wn1r11, c2=bn1
    int t2 = t - 1024; int j = t2 >> 3, c = t2 & 7;
    float v = (c == 0) ? Wn1[10 * 128 + j] : (c == 1) ? Wn1[11 * 128 + j]
            : (c == 2) ? bn1[j] : 0.0f;
    wsA[t] = f2bf(v);
  } else if (t < 2304) {                // A4 compact: 2 rows of Wn2^T
    int t2 = t - 2048; int jp = t2 >> 7, k = t2 & 127;
    wsA[t] = f2bf(Wn2[k * 2 + jp]);
  } else if (t >= 4096 && t < 20480) {  // A2 = We2^T
    int t2 = t - 4096; int j = t2 >> 7, k = t2 & 127;
    wsA[t] = f2bf(We2[k * 128 + j]);
  } else if (t >= 20480 && t < 36864) { // A3 main = Wn1[12:140]^T
    int t2 = t - 20480; int j = t2 >> 7, k = t2 & 127;
    wsA[t] = f2bf(Wn1[(12 + k) * 128 + j]);
  }
}

// ---------------- main fused kernel ----------------
#define NTILES 8192   // 262144 rows / 32 rows per tile

__global__ __launch_bounds__(128) __attribute__((amdgpu_waves_per_eu(2, 2)))
void gn_main(
    const float* __restrict__ x, const float* __restrict__ u,
    const float* __restrict__ nmean, const float* __restrict__ nstd,
    const float* __restrict__ emean, const float* __restrict__ estd,
    const float* __restrict__ be2, const float* __restrict__ bn2,
    const unsigned short* __restrict__ wsA,
    float* __restrict__ out)
{
  __shared__ __align__(16) unsigned short bufE1[32 * 128];  // 8KB
  __shared__ __align__(16) unsigned short bufE2[32 * 128];  // 8KB
  __shared__ __align__(16) unsigned short bufHD[32 * 128];  // 8KB
  __shared__ __align__(16) unsigned short aLDS[2304];       // A1c|A3e|A4c, 4.5KB

  const int tid  = threadIdx.x;
  const int lane = tid & 63;
  const int Mg   = tid >> 6;     // wave = feature half 0/1
  const int c15  = lane & 15;
  const int g    = lane >> 4;    // 0..3

  // ---- copy compact A-images into LDS (one time) ----
  for (int t = tid; t < 1152; t += 128)
    ((unsigned*)aLDS)[t] = ((const unsigned*)wsA)[t];

  // ---- resident A-operand fragments: A2, A3-main only (128 regs = AGPR capacity) ----
  bf16x8 A2f[4][4], A3f[4][4];
  const int jbw = Mg * 64;
  #pragma unroll
  for (int m = 0; m < 4; ++m) {
    int j = jbw + m * 16 + c15;
    #pragma unroll
    for (int kk = 0; kk < 4; ++kk) {
      A2f[m][kk] = *(const bf16x8*)(wsA + 4096  + j * 128 + kk * 32 + g * 8);
      A3f[m][kk] = *(const bf16x8*)(wsA + 20480 + j * 128 + kk * 32 + g * 8);
    }
  }

  const float nm0 = nmean[0], nm1 = nmean[1];
  const float is0 = 1.0f / nstd[0], is1 = 1.0f / nstd[1];
  const float em0 = emean[0], ie0 = 1.0f / estd[0];
  const float cea1 = (0.0f - emean[1]) / estd[1];
  const float cea2 = (0.0f - emean[2]) / estd[2];
  const float bn20 = bn2[0], bn21 = bn2[1];
  const unsigned cpkw = cvtpk(cea2, 1.0f);   // B dword3: [cea2, 1.0]

  // ---- prefetch first tile's x/u ----
  float4 xv[2]; float uv[2];
  {
    int t0 = blockIdx.x;
    if (g == 0) {
      #pragma unroll
      for (int n = 0; n < 2; ++n) {
        int b = t0 * 16 + n * 8 + (c15 >> 1);
        xv[n] = *(const float4*)(x + b * 4);
        uv[n] = u[b];
      }
    }
  }
  __syncthreads();   // aLDS ready

  for (int tile = blockIdx.x; tile < NTILES; tile += gridDim.x) {
    const int rowbase = tile * 32;
    unsigned pks[2];
    bf16x8 Bv[2];

    // ---------- load A1 fragments from LDS (transient; overlaps B-build VALU) ----------
    bf16x8 A1t[4];
    #pragma unroll
    for (int m = 0; m < 4; ++m) {
      uint4 av = (uint4){0u, 0u, 0u, 0u};
      if (g == 0) av = *(const uint4*)((const char*)aLDS + (jbw + m * 16 + c15) * 16);
      U4B ta; ta.u = av; A1t[m] = ta.b;
    }

    // ---------- build G1 B-operands in registers ----------
    #pragma unroll
    for (int n = 0; n < 2; ++n) {
      uint4 bu = (uint4){0u, 0u, 0u, 0u};
      if (g == 0) {                     // only k=0..7 nonzero; g==0 lanes hold them
        float a0 = (xv[n].x - nm0) * is0;   // node0 theta
        float a1 = (xv[n].z - nm1) * is1;   // node0 v
        float b0 = (xv[n].y - nm0) * is0;   // node1 theta
        float b1 = (xv[n].w - nm1) * is1;   // node1 v
        bool  e  = (c15 & 1);               // row parity = edge index
        float s0 = e ? b0 : a0, s1 = e ? b1 : a1;   // sender  feats
        float r0 = e ? a0 : b0, r1 = e ? a1 : b1;   // receiver feats
        float ea0 = (uv[n] - em0) * ie0;
        bu.x = cvtpk(s0, s1);
        bu.y = cvtpk(r0, r1);
        bu.z = cvtpk(ea0, cea1);
        bu.w = cpkw;
      }
      pks[n] = bu.x;                    // sender feats, reused as G3 node feats
      U4B t; t.u = bu; Bv[n] = t.b;
    }

    // ---------- prefetch next tile's x/u (hidden under 3 barriers) ----------
    {
      int nt = tile + (int)gridDim.x;
      if (nt < NTILES && g == 0) {
        #pragma unroll
        for (int n = 0; n < 2; ++n) {
          int b = nt * 16 + n * 8 + (c15 >> 1);
          xv[n] = *(const float4*)(x + b * 4);
          uv[n] = u[b];
        }
      }
    }

    f32x4 acc[4][2];

    // ---------- G1: e1 = relu(A1 @ in32) -> bufE1 ----------
    #pragma unroll
    for (int m = 0; m < 4; ++m)
      #pragma unroll
      for (int n = 0; n < 2; ++n) acc[m][n] = (f32x4){0.f, 0.f, 0.f, 0.f};
    #pragma unroll
    for (int n = 0; n < 2; ++n)
      #pragma unroll
      for (int m = 0; m < 4; ++m)
        acc[m][n] = __builtin_amdgcn_mfma_f32_16x16x32_bf16(A1t[m], Bv[n], acc[m][n], 0, 0, 0);
    #pragma unroll
    for (int m = 0; m < 4; ++m) {
      int jb2 = (jbw + m * 16 + g * 4) * 2;
      #pragma unroll
      for (int n = 0; n < 2; ++n) {
        int row = n * 16 + c15;
        f32x4 v = acc[m][n];
        uint2 pk;
        pk.x = cvtpk(fmaxf(v[0], 0.f), fmaxf(v[1], 0.f));
        pk.y = cvtpk(fmaxf(v[2], 0.f), fmaxf(v[3], 0.f));
        *(uint2*)((char*)bufE1 + row * 256 + (jb2 ^ ((row & 7) << 4))) = pk;
      }
    }
    __syncthreads();

    // ---------- G2: e2 = relu(A2 @ e1 + be2) -> bufE2 (be2 as C-init) ----------
    #pragma unroll
    for (int m = 0; m < 4; ++m) {
      f32x4 bz = *(const f32x4*)(be2 + jbw + m * 16 + g * 4);
      acc[m][0] = bz; acc[m][1] = bz;
    }
    #pragma unroll
    for (int n = 0; n < 2; ++n) {
      int row = n * 16 + c15;
      int rb = row * 256, sw = (row & 7) << 4;
      #pragma unroll
      for (int kk = 0; kk < 4; ++kk) {
        bf16x8 B = *(const bf16x8*)((const char*)bufE1 + rb + ((kk * 64 + g * 16) ^ sw));
        #pragma unroll
        for (int m = 0; m < 4; ++m)
          acc[m][n] = __builtin_amdgcn_mfma_f32_16x16x32_bf16(A2f[m][kk], B, acc[m][n], 0, 0, 0);
      }
    }
    #pragma unroll
    for (int m = 0; m < 4; ++m) {
      int jb2 = (jbw + m * 16 + g * 4) * 2;
      #pragma unroll
      for (int n = 0; n < 2; ++n) {
        int row = n * 16 + c15;
        f32x4 v = acc[m][n];
        uint2 pk;
        pk.x = cvtpk(fmaxf(v[0], 0.f), fmaxf(v[1], 0.f));
        pk.y = cvtpk(fmaxf(v[2], 0.f), fmaxf(v[3], 0.f));
        *(uint2*)((char*)bufE2 + row * 256 + (jb2 ^ ((row & 7) << 4))) = pk;
      }
    }
    __syncthreads();

    // ---------- G3: hdd = relu(A3 @ [e2[row^1]; sender,1]) -> bufHD ----------
    bf16x8 A3et[4];
    #pragma unroll
    for (int m = 0; m < 4; ++m) {   // transient ext fragments from LDS
      uint4 av = (uint4){0u, 0u, 0u, 0u};
      if (g == 0) av = *(const uint4*)((const char*)aLDS + 2048 + (jbw + m * 16 + c15) * 16);
      U4B ta; ta.u = av; A3et[m] = ta.b;
    }
    #pragma unroll
    for (int m = 0; m < 4; ++m)
      #pragma unroll
      for (int n = 0; n < 2; ++n) acc[m][n] = (f32x4){0.f, 0.f, 0.f, 0.f};
    #pragma unroll
    for (int n = 0; n < 2; ++n) {
      int rr0 = n * 16 + c15;
      int rsw = rr0 ^ 1;                       // aggregation = paired-row swap
      int rb = rsw * 256, sw = (rsw & 7) << 4;
      #pragma unroll
      for (int kk = 0; kk < 4; ++kk) {
        bf16x8 B = *(const bf16x8*)((const char*)bufE2 + rb + ((kk * 64 + g * 16) ^ sw));
        #pragma unroll
        for (int m = 0; m < 4; ++m)
          acc[m][n] = __builtin_amdgcn_mfma_f32_16x16x32_bf16(A3f[m][kk], B, acc[m][n], 0, 0, 0);
      }
      // K-chunk 4: node feats (= sender feats saved from G1) + const-1 (bn1 column)
      uint4 b4u = (uint4){0u, 0u, 0u, 0u};
      if (g == 0) { b4u.x = pks[n]; b4u.y = 0x00003F80u; }
      U4B t4; t4.u = b4u;
      #pragma unroll
      for (int m = 0; m < 4; ++m)
        acc[m][n] = __builtin_amdgcn_mfma_f32_16x16x32_bf16(A3et[m], t4.b, acc[m][n], 0, 0, 0);
    }
    #pragma unroll
    for (int m = 0; m < 4; ++m) {
      int jb2 = (jbw + m * 16 + g * 4) * 2;
      #pragma unroll
      for (int n = 0; n < 2; ++n) {
        int row = n * 16 + c15;
        f32x4 v = acc[m][n];
        uint2 pk;
        pk.x = cvtpk(fmaxf(v[0], 0.f), fmaxf(v[1], 0.f));
        pk.y = cvtpk(fmaxf(v[2], 0.f), fmaxf(v[3], 0.f));
        *(uint2*)((char*)bufHD + row * 256 + (jb2 ^ ((row & 7) << 4))) = pk;
      }
    }
    __syncthreads();

    // ---------- G4: delta = A4 @ hdd + bn2 (C-init), store direct ----------
    {
      int rr = Mg * 16 + c15;
      int rb = rr * 256, sw = (rr & 7) << 4;
      f32x4 a4 = (f32x4){bn20, bn21, 0.f, 0.f};
      #pragma unroll
      for (int kk = 0; kk < 4; ++kk) {
        uint4 av = (uint4){0u, 0u, 0u, 0u};   // transient A4 fragment from LDS
        if (c15 < 2) av = *(const uint4*)((const char*)aLDS + 4096 + c15 * 256 + kk * 64 + g * 16);
        U4B ta; ta.u = av;
        bf16x8 B = *(const bf16x8*)((const char*)bufHD + rb + ((kk * 64 + g * 16) ^ sw));
        a4 = __builtin_amdgcn_mfma_f32_16x16x32_bf16(ta.b, B, a4, 0, 0, 0);
      }
      if (g == 0) {                // lane holds delta c0,c1 for row rr
        int gr = rowbase + rr;
        int bidx = gr >> 1, k = gr & 1;
        out[bidx * 4 + k]     = x[bidx * 4 + k]     + a4[0];
        out[bidx * 4 + k + 2] = x[bidx * 4 + k + 2] + a4[1];
      }
    }
    // no trailing barrier: next G1 writes bufE1, whose last reads (G2) are 2 barriers back.
  }
}

extern "C" void kernel_launch(void* const* d_in, const int* in_sizes, int n_in,
                              void* d_out, int out_size, void* d_ws, size_t ws_size,
                              hipStream_t stream) {
  const float* x   = (const float*)d_in[0];
  const float* u   = (const float*)d_in[1];
  const float* nm  = (const float*)d_in[2];
  const float* ns  = (const float*)d_in[3];
  const float* em  = (const float*)d_in[4];
  const float* es  = (const float*)d_in[5];
  const float* We1 = (const float*)d_in[6];
  const float* be1 = (const float*)d_in[7];
  const float* We2 = (const float*)d_in[8];
  const float* be2 = (const float*)d_in[9];
  const float* Wn1 = (const float*)d_in[10];
  const float* bn1 = (const float*)d_in[11];
  const float* Wn2 = (const float*)d_in[12];
  const float* bn2 = (const float*)d_in[13];
  unsigned short* wsA = (unsigned short*)d_ws;   // needs 73728 bytes
  float* out = (float*)d_out;

  gn_prep<<<144, 256, 0, stream>>>(We1, be1, We2, Wn1, bn1, Wn2, wsA);
  gn_main<<<1024, 128, 0, stream>>>(x, u, nm, ns, em, es, be2, bn2, wsA, out);
}